// Round 2
// baseline (1282.554 us; speedup 1.0000x reference)
//
#include <hip/hip_runtime.h>

// DSTP-RNN fused forward: one workgroup per batch element (512 WGs x 256 thr).
// Entire encoder+decoder recurrence runs inside the kernel; encoded/Uenc live in LDS.
// LDS budget 79088 B -> 2 WG/CU (158KB of 160KB).

#define TSTEPS 128

// LDS float offsets
#define ENC   0        // 128*64   encoded (lane-major reads/writes, no pad needed)
#define UENC  8192     // 128*68   Uenc padded rows (tt-major b128 reads -> stride 68 avoids bank conflicts)
#define CTL   16896    // 64*12    conv tile c_t, padded stride 12
#define UEL   17664    // 1024     Ue_w staged (encoder) / decoder small-weights pool
#define XV    18688    // 256      x buffer [0..127] | ve [128..255]
#define HSB   18944    // 128      h|s (encoder), d|sp (decoder)
#define GBUF  19072    // 256      LSTM preacts / c_t partial scratch
#define RED   19328    // 96       e vector + scalars
#define IMG   19424    // 84       9x9 image
#define WIB   19508    // 8        w_in
#define CTV   19516    // 64       decoder c_t (c_last survives loop)
#define LBUF  19580    // 128      l / beta
#define TYP   19708    // 64       final projection tmp
#define SMEMF 19772

__device__ __forceinline__ float rcpf(float x) { return __builtin_amdgcn_rcpf(x); }
__device__ __forceinline__ float fsigm(float x) { return rcpf(1.0f + __expf(-x)); }
__device__ __forceinline__ float ftanh(float x) { return 1.0f - 2.0f * rcpf(1.0f + __expf(2.0f * x)); }

__global__ __launch_bounds__(256, 2) void dstp_kernel(
    const float* __restrict__ Xh,   const float* __restrict__ yh,
    const float* __restrict__ convw,const float* __restrict__ convb,
    const float* __restrict__ Wew,  const float* __restrict__ Web,
    const float* __restrict__ Uew,  const float* __restrict__ vew,
    const float* __restrict__ eWih, const float* __restrict__ eWhh,
    const float* __restrict__ ebih, const float* __restrict__ ebhh,
    const float* __restrict__ Wdw,  const float* __restrict__ Wdb,
    const float* __restrict__ Udw,  const float* __restrict__ vdw,
    const float* __restrict__ wtw,  const float* __restrict__ wtb,
    const float* __restrict__ dWih, const float* __restrict__ dWhh,
    const float* __restrict__ dbih, const float* __restrict__ dbhh,
    const float* __restrict__ Wyw,  const float* __restrict__ Wyb,
    const float* __restrict__ vyw,  const float* __restrict__ vyb,
    float* __restrict__ out)
{
    extern __shared__ float sm[];
    const int tid = threadIdx.x;
    const int b   = blockIdx.x;

    // stage Ue_w (128x8) + ve (128); zero h,s
    for (int i = tid; i < 1024; i += 256) sm[UEL + i] = Uew[i];
    if (tid < 128) { sm[XV + 128 + tid] = vew[tid]; sm[HSB + tid] = 0.0f; }
    __syncthreads();

    const int dm = tid >> 2, dq = tid & 3;

    // ===================== ENCODER =====================
    for (int t = 0; t < TSTEPS; ++t) {
        // (a) load 9x9 image
        if (tid < 81) sm[IMG + tid] = Xh[((size_t)b * TSTEPS + t) * 81 + tid];
        // (c) x[j] = [h,s] . We_w[j,:] + We_b[j]   (j = tid>>1, halves over k)
        {
            int j = tid >> 1, h = tid & 1;
            const float4* wr = reinterpret_cast<const float4*>(Wew + j * 128 + h * 64);
            const float4* hv = reinterpret_cast<const float4*>(sm + HSB + h * 64);
            float acc = 0.0f;
#pragma unroll
            for (int k = 0; k < 16; ++k) {
                float4 w = wr[k], x = hv[k];
                acc = fmaf(w.x, x.x, acc); acc = fmaf(w.y, x.y, acc);
                acc = fmaf(w.z, x.z, acc); acc = fmaf(w.w, x.w, acc);
            }
            acc += __shfl_xor(acc, 1);
            if (h == 0) sm[XV + j] = acc + Web[j];
        }
        __syncthreads();
        // (b) conv + relu -> ct[m][r]
#pragma unroll
        for (int rep = 0; rep < 2; ++rep) {
            int idx = tid + rep * 256;
            int m = idx >> 3, r = idx & 7;
            const float* kw = convw + m * 18;
            float acc = convb[m];
#pragma unroll
            for (int w = 0; w < 9; ++w) {
                acc = fmaf(sm[IMG + r * 9 + w],     kw[w],     acc);
                acc = fmaf(sm[IMG + r * 9 + 9 + w], kw[9 + w], acc);
            }
            sm[CTL + m * 12 + r] = fmaxf(acc, 0.0f);
        }
        __syncthreads();
        // (d) e[m] = sum_j tanh(x[j] + ct[m].Ue[j]) * ve[j]   (m=tid>>2, quad over j%4)
        {
            const float4 c0 = *reinterpret_cast<const float4*>(sm + CTL + dm * 12);
            const float4 c1 = *reinterpret_cast<const float4*>(sm + CTL + dm * 12 + 4);
            float eacc = 0.0f;
#pragma unroll 8
            for (int jj = 0; jj < 32; ++jj) {
                int j = (jj << 2) | dq;
                float xj  = sm[XV + j];
                float vej = sm[XV + 128 + j];
                const float4 u0 = *reinterpret_cast<const float4*>(sm + UEL + j * 8);
                const float4 u1 = *reinterpret_cast<const float4*>(sm + UEL + j * 8 + 4);
                float s = xj;
                s = fmaf(u0.x, c0.x, s); s = fmaf(u0.y, c0.y, s);
                s = fmaf(u0.z, c0.z, s); s = fmaf(u0.w, c0.w, s);
                s = fmaf(u1.x, c1.x, s); s = fmaf(u1.y, c1.y, s);
                s = fmaf(u1.z, c1.z, s); s = fmaf(u1.w, c1.w, s);
                eacc = fmaf(ftanh(s), vej, eacc);
            }
            eacc += __shfl_xor(eacc, 1);
            eacc += __shfl_xor(eacc, 2);
            if (dq == 0) sm[RED + dm] = eacc;
        }
        __syncthreads();
        // (e,f) softmax over m + w_in (wave 0)
        if (tid < 64) {
            float e = sm[RED + tid];
            float mx = e;
#pragma unroll
            for (int dd = 1; dd < 64; dd <<= 1) mx = fmaxf(mx, __shfl_xor(mx, dd));
            float ex = __expf(e - mx);
            float s = ex;
#pragma unroll
            for (int dd = 1; dd < 64; dd <<= 1) s += __shfl_xor(s, dd);
            float al = ex * rcpf(s);
            float p[8];
#pragma unroll
            for (int c = 0; c < 8; ++c) p[c] = al * sm[CTL + tid * 12 + c];
#pragma unroll
            for (int dd = 1; dd < 64; dd <<= 1) {
#pragma unroll
                for (int c = 0; c < 8; ++c) p[c] += __shfl_xor(p[c], dd);
            }
            if (tid == 0) {
#pragma unroll
                for (int c = 0; c < 8; ++c) sm[WIB + c] = p[c];
            }
        }
        __syncthreads();
        // (g) LSTM preact g[j] (j = tid)
        {
            const float4* wih = reinterpret_cast<const float4*>(eWih + tid * 8);
            float4 a0 = wih[0], a1 = wih[1];
            const float4 w0 = *reinterpret_cast<const float4*>(sm + WIB);
            const float4 w1 = *reinterpret_cast<const float4*>(sm + WIB + 4);
            float acc = ebih[tid] + ebhh[tid];
            acc = fmaf(a0.x, w0.x, acc); acc = fmaf(a0.y, w0.y, acc);
            acc = fmaf(a0.z, w0.z, acc); acc = fmaf(a0.w, w0.w, acc);
            acc = fmaf(a1.x, w1.x, acc); acc = fmaf(a1.y, w1.y, acc);
            acc = fmaf(a1.z, w1.z, acc); acc = fmaf(a1.w, w1.w, acc);
            const float4* whh = reinterpret_cast<const float4*>(eWhh + tid * 64);
            const float4* hv  = reinterpret_cast<const float4*>(sm + HSB);
#pragma unroll
            for (int k = 0; k < 16; ++k) {
                float4 w = whh[k], x = hv[k];
                acc = fmaf(w.x, x.x, acc); acc = fmaf(w.y, x.y, acc);
                acc = fmaf(w.z, x.z, acc); acc = fmaf(w.w, x.w, acc);
            }
            sm[GBUF + tid] = acc;
        }
        __syncthreads();
        // (h) gates -> h,s ; write encoded row
        if (tid < 64) {
            float gi = sm[GBUF + tid],       gf = sm[GBUF + 64 + tid];
            float gg = sm[GBUF + 128 + tid], go = sm[GBUF + 192 + tid];
            float c = fsigm(gf) * sm[HSB + 64 + tid] + fsigm(gi) * ftanh(gg);
            float h = fsigm(go) * ftanh(c);
            sm[HSB + tid] = h;
            sm[HSB + 64 + tid] = c;
            sm[ENC + t * 64 + tid] = h;
        }
        __syncthreads();
        // (i) Uenc[t][j] = h . Ud_w[j,:]   (j = tid>>2, quad over k)
        {
            int j = tid >> 2, q = tid & 3;
            const float4* ud = reinterpret_cast<const float4*>(Udw + j * 64 + q * 16);
            const float4* hv = reinterpret_cast<const float4*>(sm + HSB + q * 16);
            float acc = 0.0f;
#pragma unroll
            for (int k = 0; k < 4; ++k) {
                float4 w = ud[k], x = hv[k];
                acc = fmaf(w.x, x.x, acc); acc = fmaf(w.y, x.y, acc);
                acc = fmaf(w.z, x.z, acc); acc = fmaf(w.w, x.w, acc);
            }
            acc += __shfl_xor(acc, 1);
            acc += __shfl_xor(acc, 2);
            if (q == 0) sm[UENC + t * 68 + j] = acc;
        }
        __syncthreads();
    }

    // stage decoder constants into UEL (Ue_w no longer needed)
    if (tid < 64) sm[UEL + tid] = vdw[tid];              // vd: 0..63
    if (tid < 65) sm[UEL + 64 + tid] = wtw[tid];         // wt: 64..128
    sm[UEL + 192 + tid] = dWih[tid];                     // dWih: 192..447
    sm[UEL + 448 + tid] = dbih[tid] + dbhh[tid];         // bias sum: 448..703
    if (tid < 64) sm[UEL + 704 + tid] = Wdb[tid];        // 704..767
    if (tid < 64) sm[UEL + 768 + tid] = Wyb[tid];        // 768..831
    if (tid < 64) sm[UEL + 832 + tid] = vyw[tid];        // 832..895
    if (tid < 128) sm[HSB + tid] = 0.0f;                 // d, sp = 0
    __syncthreads();

    // ===================== DECODER =====================
    for (int t = 0; t < TSTEPS; ++t) {
        // (a) x1[j] = [d,sp] . Wd_w[j,:] + Wd_b[j]
        {
            int j = tid >> 2, q = tid & 3;
            const float4* wd = reinterpret_cast<const float4*>(Wdw + j * 128 + q * 32);
            const float4* dv = reinterpret_cast<const float4*>(sm + HSB + q * 32);
            float acc = 0.0f;
#pragma unroll
            for (int k = 0; k < 8; ++k) {
                float4 w = wd[k], x = dv[k];
                acc = fmaf(w.x, x.x, acc); acc = fmaf(w.y, x.y, acc);
                acc = fmaf(w.z, x.z, acc); acc = fmaf(w.w, x.w, acc);
            }
            acc += __shfl_xor(acc, 1);
            acc += __shfl_xor(acc, 2);
            if (q == 0) sm[XV + j] = acc + sm[UEL + 704 + j];
        }
        __syncthreads();
        // (b) l[tt] = sum_j tanh(x1[j] + Uenc[tt][j]) * vd[j]   (tt = tid>>1)
        {
            int tt2 = tid >> 1, h = tid & 1;
            const float* ur = sm + UENC + tt2 * 68 + h * 32;
            const float* xr = sm + XV + h * 32;
            const float* vr = sm + UEL + h * 32;
            float acc = 0.0f;
#pragma unroll
            for (int j4 = 0; j4 < 8; ++j4) {
                float4 u = *reinterpret_cast<const float4*>(ur + j4 * 4);
                float4 x = *reinterpret_cast<const float4*>(xr + j4 * 4);
                float4 v = *reinterpret_cast<const float4*>(vr + j4 * 4);
                acc = fmaf(ftanh(x.x + u.x), v.x, acc);
                acc = fmaf(ftanh(x.y + u.y), v.y, acc);
                acc = fmaf(ftanh(x.z + u.z), v.z, acc);
                acc = fmaf(ftanh(x.w + u.w), v.w, acc);
            }
            acc += __shfl_xor(acc, 1);
            if (h == 0) sm[LBUF + tt2] = acc;
        }
        __syncthreads();
        // (c) softmax over 128 tt (wave 0, 2 per lane)
        if (tid < 64) {
            float v0 = sm[LBUF + tid], v1 = sm[LBUF + 64 + tid];
            float mx = fmaxf(v0, v1);
#pragma unroll
            for (int dd = 1; dd < 64; dd <<= 1) mx = fmaxf(mx, __shfl_xor(mx, dd));
            float e0 = __expf(v0 - mx), e1 = __expf(v1 - mx);
            float s = e0 + e1;
#pragma unroll
            for (int dd = 1; dd < 64; dd <<= 1) s += __shfl_xor(s, dd);
            float r = rcpf(s);
            sm[LBUF + tid] = e0 * r;
            sm[LBUF + 64 + tid] = e1 * r;
        }
        __syncthreads();
        // (d) c_t partials: j = tid&63 lanes, tt-chunk = tid>>6
        {
            int j = tid & 63, q = tid >> 6;
            float acc = 0.0f;
#pragma unroll 8
            for (int i = 0; i < 32; ++i) {
                int ttk = (q << 5) + i;
                acc = fmaf(sm[LBUF + ttk], sm[ENC + ttk * 64 + j], acc);
            }
            sm[GBUF + tid] = acc;
        }
        __syncthreads();
        // (d2/e) finish c_t + y_tilda (wave 0)
        if (tid < 64) {
            float cv = sm[GBUF + tid] + sm[GBUF + 64 + tid] +
                       sm[GBUF + 128 + tid] + sm[GBUF + 192 + tid];
            sm[CTV + tid] = cv;
            float p = cv * sm[UEL + 64 + tid];
#pragma unroll
            for (int dd = 1; dd < 64; dd <<= 1) p += __shfl_xor(p, dd);
            if (tid == 0)
                sm[RED + 64] = p + yh[(size_t)b * TSTEPS + t] * sm[UEL + 128] + wtb[0];
        }
        __syncthreads();
        // (f) dec LSTM preact
        {
            float yt = sm[RED + 64];
            float acc = fmaf(yt, sm[UEL + 192 + tid], sm[UEL + 448 + tid]);
            const float4* whh = reinterpret_cast<const float4*>(dWhh + tid * 64);
            const float4* dv  = reinterpret_cast<const float4*>(sm + HSB);
#pragma unroll
            for (int k = 0; k < 16; ++k) {
                float4 w = whh[k], x = dv[k];
                acc = fmaf(w.x, x.x, acc); acc = fmaf(w.y, x.y, acc);
                acc = fmaf(w.z, x.z, acc); acc = fmaf(w.w, x.w, acc);
            }
            sm[GBUF + tid] = acc;
        }
        __syncthreads();
        // (g) gates -> d, sp
        if (tid < 64) {
            float gi = sm[GBUF + tid],       gf = sm[GBUF + 64 + tid];
            float gg = sm[GBUF + 128 + tid], go = sm[GBUF + 192 + tid];
            float c = fsigm(gf) * sm[HSB + 64 + tid] + fsigm(gi) * ftanh(gg);
            float dnew = fsigm(go) * ftanh(c);
            sm[HSB + tid] = dnew;
            sm[HSB + 64 + tid] = c;
        }
        __syncthreads();
    }

    // ===================== HEAD =====================
    {
        int p = tid >> 2, q = tid & 3;
        const float4* wy = reinterpret_cast<const float4*>(Wyw + p * 128 + q * 32);
        const float4* sv = reinterpret_cast<const float4*>(
            (q < 2) ? (sm + HSB + q * 32) : (sm + CTV + (q - 2) * 32));
        float acc = 0.0f;
#pragma unroll
        for (int k = 0; k < 8; ++k) {
            float4 w = wy[k], x = sv[k];
            acc = fmaf(w.x, x.x, acc); acc = fmaf(w.y, x.y, acc);
            acc = fmaf(w.z, x.z, acc); acc = fmaf(w.w, x.w, acc);
        }
        acc += __shfl_xor(acc, 1);
        acc += __shfl_xor(acc, 2);
        if (q == 0) sm[TYP + p] = acc + sm[UEL + 768 + p];
    }
    __syncthreads();
    if (tid < 64) {
        float v = sm[TYP + tid] * sm[UEL + 832 + tid];
#pragma unroll
        for (int dd = 1; dd < 64; dd <<= 1) v += __shfl_xor(v, dd);
        if (tid == 0) out[b] = v + vyb[0];
    }
}

extern "C" void kernel_launch(void* const* d_in, const int* in_sizes, int n_in,
                              void* d_out, int out_size, void* d_ws, size_t ws_size,
                              hipStream_t stream) {
    const float* A[26];
    for (int i = 0; i < 26; ++i) A[i] = (const float*)d_in[i];
    (void)in_sizes; (void)n_in; (void)d_ws; (void)ws_size; (void)out_size;

    (void)hipFuncSetAttribute(reinterpret_cast<const void*>(dstp_kernel),
                              hipFuncAttributeMaxDynamicSharedMemorySize,
                              SMEMF * 4);

    dstp_kernel<<<dim3(512), dim3(256), SMEMF * 4, stream>>>(
        A[0], A[1], A[2], A[3], A[4], A[5], A[6], A[7], A[8], A[9],
        A[10], A[11], A[12], A[13], A[14], A[15], A[16], A[17], A[18], A[19],
        A[20], A[21], A[22], A[23], A[24], A[25], (float*)d_out);
}